// Round 5
// baseline (307.784 us; speedup 1.0000x reference)
//
#include <hip/hip_runtime.h>

#define EPS 1e-5f

typedef __bf16 bf16x8 __attribute__((ext_vector_type(8)));
typedef __bf16 bf16x4 __attribute__((ext_vector_type(4)));
typedef unsigned short ushort8 __attribute__((ext_vector_type(8)));
typedef float f32x4 __attribute__((ext_vector_type(4)));

static __device__ __forceinline__ unsigned short f2bf(float f) {
  unsigned int u = __float_as_uint(f);
  u += 0x7fffu + ((u >> 16) & 1u);
  return (unsigned short)(u >> 16);
}

// ---------------- ws layout (bytes) ----------------
// h2   (bf16, NHWC [128][1024][128])             : 0 .. 33554432
// xbf  (bf16, NHWC [128][1024][512])             : 33554432 .. 167772160
// w1b  (bf16, [128 oc][512 c], bn2-scale folded) : 167772160 .. +131072
// w2b  (bf16, [32 oc][9 tap][128 c])             : 167903232 .. +73728
// bias2(f32 [128])                               : 167976960 .. +512
// s1   (f32 [512])                               : 167977472 .. +2048
// b1   (f32 [512])                               : 167979520 .. +2048
// psum (f32 [512 c][1024 blk])                   : 167981568 .. +2097152
// psq  (f32 [512 c][1024 blk])                   : 170078720 .. +2097152

// ---- kernel 1: stats partials + concat-copy + bf16 NHWC shadow (LDS transpose) ----
// blocks 0..1023: (n, pq) tile = 512 c x 128 px. blocks 1024..1424: weight prep.
__global__ void __launch_bounds__(256) k1_kernel(
    const float* __restrict__ x, float* __restrict__ out,
    unsigned short* __restrict__ xbf,
    float* __restrict__ psum, float* __restrict__ psq,
    const float* __restrict__ w1, const float* __restrict__ gamma2,
    const float* __restrict__ beta2, const float* __restrict__ mean2,
    const float* __restrict__ var2, const float* __restrict__ w2,
    unsigned short* __restrict__ w1b, unsigned short* __restrict__ w2b,
    float* __restrict__ bias2) {
  const int t = threadIdx.x;
  if (blockIdx.x >= 1024) {
    int idx = (blockIdx.x - 1024) * 256 + t;
    if (idx < 128 * 512) {
      int oc = idx >> 9;
      float s2 = gamma2[oc] * rsqrtf(var2[oc] + EPS);
      w1b[idx] = f2bf(w1[idx] * s2);
    } else if (idx < 128 * 512 + 32 * 1152) {
      int i2 = idx - 128 * 512;
      int oc = i2 / 1152;
      int rem = i2 - oc * 1152;
      int tap = rem >> 7;
      int c = rem & 127;
      w2b[i2] = f2bf(w2[(oc * 128 + c) * 9 + tap]);
    } else if (idx < 128 * 512 + 32 * 1152 + 128) {
      int oc = idx - (128 * 512 + 32 * 1152);
      float s2 = gamma2[oc] * rsqrtf(var2[oc] + EPS);
      bias2[oc] = beta2[oc] - mean2[oc] * s2;
    }
    return;
  }

  // tile: [128 px][72 bf16] (row stride 144B); red: per-wave stats partials
  __shared__ __align__(16) unsigned short tile[128 * 72];
  __shared__ float red[2][4][64];

  const int n = blockIdx.x >> 3;
  const int pq = blockIdx.x & 7;        // 128-px slab
  const int q = t & 15;                  // channel quad id (4 ch)
  const int ph = t >> 4;                 // 0..15 px-chunk phase
  const int lane = t & 63;
  const int wv = t >> 6;

  const f32x4* __restrict__ x4 = (const f32x4*)x;
  f32x4* out4 = (f32x4*)out;

  for (int cb = 0; cb < 8; ++cb) {
    const int c0 = cb * 64 + q * 4;
    float sum[4] = {0.f, 0.f, 0.f, 0.f}, sq[4] = {0.f, 0.f, 0.f, 0.f};
#pragma unroll
    for (int i = 0; i < 2; ++i) {
      const int px4 = i * 16 + ph;       // 0..31 (x16B within 128 px)
      f32x4 v[4];
#pragma unroll
      for (int j = 0; j < 4; ++j) {
        const size_t gi = (((size_t)n * 512 + c0 + j) << 8) + pq * 32 + px4;
        v[j] = __builtin_nontemporal_load(&x4[gi]);
        const size_t go = (((size_t)n * 544 + c0 + j) << 8) + pq * 32 + px4;
        __builtin_nontemporal_store(v[j], &out4[go]);
        sum[j] += v[j][0] + v[j][1] + v[j][2] + v[j][3];
        sq[j] += v[j][0] * v[j][0] + v[j][1] * v[j][1] +
                 v[j][2] * v[j][2] + v[j][3] * v[j][3];
      }
      // register 4x4 transpose -> LDS rows (px), cols (ch)
#pragma unroll
      for (int p2 = 0; p2 < 4; ++p2) {
        bf16x4 bv;
        bv[0] = (__bf16)v[0][p2];
        bv[1] = (__bf16)v[1][p2];
        bv[2] = (__bf16)v[2][p2];
        bv[3] = (__bf16)v[3][p2];
        *(bf16x4*)&tile[(size_t)(px4 * 4 + p2) * 72 + q * 4] = bv;
      }
    }
    // intra-wave reduce across the 4 lanes sharing q (lanes q, q+16, q+32, q+48)
#pragma unroll
    for (int j = 0; j < 4; ++j) {
      sum[j] += __shfl_xor(sum[j], 16);
      sum[j] += __shfl_xor(sum[j], 32);
      sq[j] += __shfl_xor(sq[j], 16);
      sq[j] += __shfl_xor(sq[j], 32);
    }
    if (lane < 16) {
#pragma unroll
      for (int j = 0; j < 4; ++j) {
        red[0][wv][q * 4 + j] = sum[j];
        red[1][wv][q * 4 + j] = sq[j];
      }
    }
    __syncthreads();
    // dump tile -> xbf NHWC (coalesced 16B stores)
#pragma unroll
    for (int r = 0; r < 4; ++r) {
      const int sl = r * 256 + t;        // 1024 slots = 128 rows x 8 chunks
      const int pl = sl >> 3, co = sl & 7;
      bf16x8 vv = *(const bf16x8*)&tile[(size_t)pl * 72 + co * 8];
      *(bf16x8*)(xbf + ((size_t)(n * 1024 + pq * 128 + pl)) * 512 + cb * 64 + co * 8) = vv;
    }
    // cross-wave stats: threads 0..63 finalize 64 channels of this cb
    if (t < 64) {
      float S = red[0][0][t] + red[0][1][t] + red[0][2][t] + red[0][3][t];
      float Q = red[1][0][t] + red[1][1][t] + red[1][2][t] + red[1][3][t];
      psum[(size_t)(cb * 64 + t) * 1024 + blockIdx.x] = S;
      psq[(size_t)(cb * 64 + t) * 1024 + blockIdx.x] = Q;
    }
    __syncthreads();
  }
}

// ---- kernel 1b: reduce partials -> s1/b1 (deterministic) ----
__global__ void __launch_bounds__(256) reduce_kernel(
    const float* __restrict__ psum, const float* __restrict__ psq,
    const float* __restrict__ g1, const float* __restrict__ be1,
    float* __restrict__ s1, float* __restrict__ b1) {
  const int c = blockIdx.x;
  const int t = threadIdx.x;
  float S = 0.f, Q = 0.f;
#pragma unroll
  for (int k = 0; k < 4; ++k) {
    S += psum[(size_t)c * 1024 + k * 256 + t];
    Q += psq[(size_t)c * 1024 + k * 256 + t];
  }
  for (int off = 32; off > 0; off >>= 1) {
    S += __shfl_down(S, off);
    Q += __shfl_down(Q, off);
  }
  __shared__ float ls[2][4];
  const int w = t >> 6;
  if ((t & 63) == 0) { ls[0][w] = S; ls[1][w] = Q; }
  __syncthreads();
  if (t == 0) {
    float St = ls[0][0] + ls[0][1] + ls[0][2] + ls[0][3];
    float Qt = ls[1][0] + ls[1][1] + ls[1][2] + ls[1][3];
    float mean = St * (1.0f / 131072.0f);
    float var = Qt * (1.0f / 131072.0f) - mean * mean;
    float s = g1[c] * rsqrtf(var + EPS);
    s1[c] = s;
    b1[c] = be1[c] - mean * s;
  }
}

// ---- kernel 2: bn1+relu -> 1x1 conv -> bn2+relu -> h2 (bf16 NHWC), from NHWC xbf ----
// grid: 1024 blocks (128 n x 8 slabs), 4 waves, wave = 128 oc x 32 px
__global__ void __launch_bounds__(256) conv1_kernel(
    const unsigned short* __restrict__ xbf, const unsigned short* __restrict__ w1b,
    const float* __restrict__ s1, const float* __restrict__ b1,
    const float* __restrict__ bias2, unsigned short* __restrict__ h2) {
  const int t = threadIdx.x;
  __shared__ float s1s[512], b1s[512];
  for (int cc = t; cc < 512; cc += 256) {
    s1s[cc] = s1[cc];
    b1s[cc] = b1[cc];
  }
  __syncthreads();

  const int lane = t & 63;
  const int wv = t >> 6;
  const int n = 127 - (blockIdx.x >> 3);
  const int p0w = (blockIdx.x & 7) * 128 + wv * 32;
  const int l15 = lane & 15;
  const int kb = lane >> 4;  // 0..3

  f32x4 acc[8][2];
#pragma unroll
  for (int m = 0; m < 8; ++m)
#pragma unroll
    for (int g = 0; g < 2; ++g) acc[m][g] = (f32x4){0.f, 0.f, 0.f, 0.f};

  const unsigned short* __restrict__ xn = xbf + (size_t)n * 1024 * 512;

  for (int c0 = 0; c0 < 512; c0 += 32) {
    const int cbase = c0 + kb * 8;
    float s1v[8], b1v[8];
#pragma unroll
    for (int j = 0; j < 8; ++j) {
      s1v[j] = s1s[cbase + j];
      b1v[j] = b1s[cbase + j];
    }
    bf16x8 bf[2];
#pragma unroll
    for (int g = 0; g < 2; ++g) {
      const int p = p0w + g * 16 + l15;
      bf16x8 xv = *(const bf16x8*)(xn + (size_t)p * 512 + cbase);
      bf16x8 tmp;
#pragma unroll
      for (int j = 0; j < 8; ++j) {
        float a = fmaxf(fmaf((float)xv[j], s1v[j], b1v[j]), 0.f);
        tmp[j] = (__bf16)a;
      }
      bf[g] = tmp;
    }
#pragma unroll
    for (int m = 0; m < 8; ++m) {
      bf16x8 af = *(const bf16x8*)(w1b + (size_t)(m * 16 + l15) * 512 + cbase);
#pragma unroll
      for (int g = 0; g < 2; ++g)
        acc[m][g] = __builtin_amdgcn_mfma_f32_16x16x32_bf16(af, bf[g], acc[m][g], 0, 0, 0);
    }
  }

#pragma unroll
  for (int m = 0; m < 8; ++m) {
    const int ocb = m * 16 + kb * 4;
    float bz0 = bias2[ocb + 0], bz1 = bias2[ocb + 1];
    float bz2 = bias2[ocb + 2], bz3 = bias2[ocb + 3];
#pragma unroll
    for (int g = 0; g < 2; ++g) {
      const int p = p0w + g * 16 + l15;
      bf16x4 hv;
      hv[0] = (__bf16)fmaxf(acc[m][g][0] + bz0, 0.f);
      hv[1] = (__bf16)fmaxf(acc[m][g][1] + bz1, 0.f);
      hv[2] = (__bf16)fmaxf(acc[m][g][2] + bz2, 0.f);
      hv[3] = (__bf16)fmaxf(acc[m][g][3] + bz3, 0.f);
      *(bf16x4*)(h2 + ((size_t)n * 1024 + p) * 128 + ocb) = hv;
    }
  }
}

// ---- kernel 3: 3x3 conv (pad 1) h2 -> out[:, 512:544] ----
// grid: 1024 blocks, 4 waves, wave = 32 oc x 32 px
__global__ void __launch_bounds__(256) conv2_kernel(
    const unsigned short* __restrict__ h2, const unsigned short* __restrict__ w2b,
    float* __restrict__ out) {
  const int t = threadIdx.x;
  const int lane = t & 63;
  const int wv = t >> 6;
  const int n = blockIdx.x >> 3;
  const int pbase = (blockIdx.x & 7) * 128 + wv * 32;
  const int l15 = lane & 15;
  const int kb = lane >> 4;

  f32x4 acc[2][2];
#pragma unroll
  for (int m = 0; m < 2; ++m)
#pragma unroll
    for (int g = 0; g < 2; ++g) acc[m][g] = (f32x4){0.f, 0.f, 0.f, 0.f};

  const unsigned short* __restrict__ h2n = h2 + (size_t)n * 1024 * 128;

#pragma unroll
  for (int tap = 0; tap < 9; ++tap) {
    const int dy = tap / 3 - 1;
    const int dx = tap % 3 - 1;
#pragma unroll
    for (int c0 = 0; c0 < 128; c0 += 32) {
      const int cb = c0 + kb * 8;
      bf16x8 af[2];
#pragma unroll
      for (int m = 0; m < 2; ++m)
        af[m] = *(const bf16x8*)(w2b + (size_t)(m * 16 + l15) * 1152 + tap * 128 + cb);
#pragma unroll
      for (int g = 0; g < 2; ++g) {
        const int p = pbase + g * 16 + l15;
        const int y = (p >> 5) & 31;
        const int xx = p & 31;
        const int y2 = y + dy;
        const int x2 = xx + dx;
        bf16x8 bv = __builtin_bit_cast(bf16x8, (ushort8){0, 0, 0, 0, 0, 0, 0, 0});
        if (y2 >= 0 && y2 < 32 && x2 >= 0 && x2 < 32)
          bv = *(const bf16x8*)(h2n + ((size_t)(y2 * 32 + x2)) * 128 + cb);
#pragma unroll
        for (int m = 0; m < 2; ++m)
          acc[m][g] = __builtin_amdgcn_mfma_f32_16x16x32_bf16(af[m], bv, acc[m][g], 0, 0, 0);
      }
    }
  }

#pragma unroll
  for (int m = 0; m < 2; ++m) {
    const int oc = m * 16 + kb * 4;
#pragma unroll
    for (int g = 0; g < 2; ++g) {
      const int p = pbase + g * 16 + l15;
#pragma unroll
      for (int r = 0; r < 4; ++r)
        __builtin_nontemporal_store(
            acc[m][g][r], &out[((size_t)n * 544 + 512 + oc + r) * 1024 + p]);
    }
  }
}

extern "C" void kernel_launch(void* const* d_in, const int* in_sizes, int n_in,
                              void* d_out, int out_size, void* d_ws, size_t ws_size,
                              hipStream_t stream) {
  const float* x = (const float*)d_in[0];
  const float* gamma1 = (const float*)d_in[1];
  const float* beta1 = (const float*)d_in[2];
  const float* w1 = (const float*)d_in[3];
  const float* gamma2 = (const float*)d_in[4];
  const float* beta2 = (const float*)d_in[5];
  const float* mean2 = (const float*)d_in[6];
  const float* var2 = (const float*)d_in[7];
  const float* w2 = (const float*)d_in[8];
  float* out = (float*)d_out;

  char* ws = (char*)d_ws;
  unsigned short* h2 = (unsigned short*)ws;
  unsigned short* xbf = (unsigned short*)(ws + 33554432);
  unsigned short* w1b = (unsigned short*)(ws + 167772160);
  unsigned short* w2b = (unsigned short*)(ws + 167903232);
  float* bias2 = (float*)(ws + 167976960);
  float* s1 = (float*)(ws + 167977472);
  float* b1 = (float*)(ws + 167979520);
  float* psum = (float*)(ws + 167981568);
  float* psq = (float*)(ws + 170078720);

  k1_kernel<<<1425, 256, 0, stream>>>(x, out, xbf, psum, psq,
                                      w1, gamma2, beta2, mean2, var2, w2,
                                      w1b, w2b, bias2);
  reduce_kernel<<<512, 256, 0, stream>>>(psum, psq, gamma1, beta1, s1, b1);
  conv1_kernel<<<1024, 256, 0, stream>>>(xbf, w1b, s1, b1, bias2, h2);
  conv2_kernel<<<1024, 256, 0, stream>>>(h2, w2b, out);
}

// Round 6
// 231.178 us; speedup vs baseline: 1.3314x; 1.3314x over previous
//
#include <hip/hip_runtime.h>

#define EPS 1e-5f

typedef __bf16 bf16x8 __attribute__((ext_vector_type(8)));
typedef __bf16 bf16x4 __attribute__((ext_vector_type(4)));
typedef unsigned short ushort8 __attribute__((ext_vector_type(8)));
typedef float f32x4 __attribute__((ext_vector_type(4)));

static __device__ __forceinline__ unsigned short f2bf(float f) {
  unsigned int u = __float_as_uint(f);
  u += 0x7fffu + ((u >> 16) & 1u);
  return (unsigned short)(u >> 16);
}

// ---------------- ws layout (bytes) ----------------
// h2   (bf16, NHWC [128][1024][128])             : 0 .. 33554432
// xbf  (bf16, NHWC [128][1024][512])             : 33554432 .. 167772160
// w1b  (bf16, [128 oc][512 c], bn2-scale folded) : 167772160 .. +131072
// w2b  (bf16, [32 oc][9 tap][128 c])             : 167903232 .. +73728
// bias2(f32 [128])                               : 167976960 .. +512
// s1   (f32 [512])                               : 167977472 .. +2048
// b1   (f32 [512])                               : 167979520 .. +2048
// psum (f32 [512 c][1024 blk])                   : 167981568 .. +2097152
// psq  (f32 [512 c][1024 blk])                   : 170078720 .. +2097152

// ---- kernel 1: stats partials + concat-copy + bf16 NHWC shadow ----
// blocks 0..1023 = (n, pq): 512 c x 128 px tile. blocks 1024.. : weight prep.
// Reads: half-wave (32 lanes) covers one channel's 128-px slab contiguously.
// Transpose via LDS f32 tile [128 px][65 ch] (write 4-way, read 2-way free).
__global__ void __launch_bounds__(256) k1_kernel(
    const float* __restrict__ x, float* __restrict__ out,
    unsigned short* __restrict__ xbf,
    float* __restrict__ psum, float* __restrict__ psq,
    const float* __restrict__ w1, const float* __restrict__ gamma2,
    const float* __restrict__ beta2, const float* __restrict__ mean2,
    const float* __restrict__ var2, const float* __restrict__ w2,
    unsigned short* __restrict__ w1b, unsigned short* __restrict__ w2b,
    float* __restrict__ bias2) {
  const int t = threadIdx.x;
  if (blockIdx.x >= 1024) {
    int idx = (blockIdx.x - 1024) * 256 + t;
    if (idx < 128 * 512) {
      int oc = idx >> 9;
      float s2 = gamma2[oc] * rsqrtf(var2[oc] + EPS);
      w1b[idx] = f2bf(w1[idx] * s2);
    } else if (idx < 128 * 512 + 32 * 1152) {
      int i2 = idx - 128 * 512;
      int oc = i2 / 1152;
      int rem = i2 - oc * 1152;
      int tap = rem >> 7;
      int c = rem & 127;
      w2b[i2] = f2bf(w2[(oc * 128 + c) * 9 + tap]);
    } else if (idx < 128 * 512 + 32 * 1152 + 128) {
      int oc = idx - (128 * 512 + 32 * 1152);
      float s2 = gamma2[oc] * rsqrtf(var2[oc] + EPS);
      bias2[oc] = beta2[oc] - mean2[oc] * s2;
    }
    return;
  }

  __shared__ float tileF[128 * 65];    // 33,280 B
  __shared__ float rsum_s[64], rsq_s[64];

  const int n = blockIdx.x >> 3;
  const int pq = blockIdx.x & 7;       // 128-px slab
  const int l31 = t & 31;
  const int hg = t >> 5;               // 0..7 half-group (channel-row owner)

  const f32x4* __restrict__ x4 = (const f32x4*)x;
  f32x4* out4 = (f32x4*)out;

  for (int cb = 0; cb < 8; ++cb) {
    // ---- phase A: coalesced load, copy, stats, LDS transpose-write ----
#pragma unroll
    for (int i = 0; i < 8; ++i) {
      const int r = i * 8 + hg;        // channel within cb block, 0..63
      const int c = cb * 64 + r;
      f32x4 v = __builtin_nontemporal_load(
          &x4[(((size_t)n * 512 + c) << 8) + pq * 32 + l31]);
      __builtin_nontemporal_store(
          v, &out4[(((size_t)n * 544 + c) << 8) + pq * 32 + l31]);
      float s = v[0] + v[1] + v[2] + v[3];
      float q = v[0] * v[0] + v[1] * v[1] + v[2] * v[2] + v[3] * v[3];
#pragma unroll
      for (int off = 1; off < 32; off <<= 1) {
        s += __shfl_xor(s, off);
        q += __shfl_xor(q, off);
      }
      if (l31 == 0) { rsum_s[r] = s; rsq_s[r] = q; }
#pragma unroll
      for (int p2 = 0; p2 < 4; ++p2)
        tileF[(l31 * 4 + p2) * 65 + r] = v[p2];
    }
    __syncthreads();
    // ---- phase B: read 8-channel columns, pack bf16, NHWC store ----
#pragma unroll
    for (int r2 = 0; r2 < 4; ++r2) {
      const int pl = r2 * 32 + (t >> 3);
      const int co = t & 7;
      bf16x8 bv;
#pragma unroll
      for (int j = 0; j < 8; ++j)
        bv[j] = (__bf16)tileF[pl * 65 + co * 8 + j];
      *(bf16x8*)(xbf + ((size_t)(n * 1024 + pq * 128 + pl)) * 512 + cb * 64 + co * 8) = bv;
    }
    if (t < 64) {
      psum[(size_t)(cb * 64 + t) * 1024 + blockIdx.x] = rsum_s[t];
      psq[(size_t)(cb * 64 + t) * 1024 + blockIdx.x] = rsq_s[t];
    }
    __syncthreads();
  }
}

// ---- kernel 1b: reduce partials -> s1/b1 (deterministic) ----
__global__ void __launch_bounds__(256) reduce_kernel(
    const float* __restrict__ psum, const float* __restrict__ psq,
    const float* __restrict__ g1, const float* __restrict__ be1,
    float* __restrict__ s1, float* __restrict__ b1) {
  const int c = blockIdx.x;
  const int t = threadIdx.x;
  float S = 0.f, Q = 0.f;
#pragma unroll
  for (int k = 0; k < 4; ++k) {
    S += psum[(size_t)c * 1024 + k * 256 + t];
    Q += psq[(size_t)c * 1024 + k * 256 + t];
  }
  for (int off = 32; off > 0; off >>= 1) {
    S += __shfl_down(S, off);
    Q += __shfl_down(Q, off);
  }
  __shared__ float ls[2][4];
  const int w = t >> 6;
  if ((t & 63) == 0) { ls[0][w] = S; ls[1][w] = Q; }
  __syncthreads();
  if (t == 0) {
    float St = ls[0][0] + ls[0][1] + ls[0][2] + ls[0][3];
    float Qt = ls[1][0] + ls[1][1] + ls[1][2] + ls[1][3];
    float mean = St * (1.0f / 131072.0f);
    float var = Qt * (1.0f / 131072.0f) - mean * mean;
    float s = g1[c] * rsqrtf(var + EPS);
    s1[c] = s;
    b1[c] = be1[c] - mean * s;
  }
}

// ---- kernel 2: bn1+relu -> 1x1 conv -> bn2+relu -> h2 (bf16 NHWC) ----
// grid: 512 blocks (128 n x 4 quarters), 4 waves, wave = 128 oc x 64 px.
// n DESCENDING: consume freshest xbf L3 lines first.
__global__ void __launch_bounds__(256, 2) conv1_kernel(
    const unsigned short* __restrict__ xbf, const unsigned short* __restrict__ w1b,
    const float* __restrict__ s1, const float* __restrict__ b1,
    const float* __restrict__ bias2, unsigned short* __restrict__ h2) {
  const int t = threadIdx.x;
  __shared__ float s1s[512], b1s[512];
  for (int cc = t; cc < 512; cc += 256) {
    s1s[cc] = s1[cc];
    b1s[cc] = b1[cc];
  }
  __syncthreads();

  const int lane = t & 63;
  const int wv = t >> 6;
  const int n = 127 - (blockIdx.x >> 2);
  const int p0w = (blockIdx.x & 3) * 256 + wv * 64;
  const int l15 = lane & 15;
  const int kb = lane >> 4;  // 0..3

  f32x4 acc[8][4];
#pragma unroll
  for (int m = 0; m < 8; ++m)
#pragma unroll
    for (int g = 0; g < 4; ++g) acc[m][g] = (f32x4){0.f, 0.f, 0.f, 0.f};

  const unsigned short* __restrict__ xn = xbf + (size_t)n * 1024 * 512;

  for (int c0 = 0; c0 < 512; c0 += 32) {
    const int cbase = c0 + kb * 8;
    float s1v[8], b1v[8];
#pragma unroll
    for (int j = 0; j < 8; ++j) {
      s1v[j] = s1s[cbase + j];
      b1v[j] = b1s[cbase + j];
    }
    bf16x8 bf[4];
#pragma unroll
    for (int g = 0; g < 4; ++g) {
      const int p = p0w + g * 16 + l15;
      bf16x8 xv = *(const bf16x8*)(xn + (size_t)p * 512 + cbase);
      bf16x8 tmp;
#pragma unroll
      for (int j = 0; j < 8; ++j) {
        float a = fmaxf(fmaf((float)xv[j], s1v[j], b1v[j]), 0.f);
        tmp[j] = (__bf16)a;
      }
      bf[g] = tmp;
    }
#pragma unroll
    for (int m = 0; m < 8; ++m) {
      bf16x8 af = *(const bf16x8*)(w1b + (size_t)(m * 16 + l15) * 512 + cbase);
#pragma unroll
      for (int g = 0; g < 4; ++g)
        acc[m][g] = __builtin_amdgcn_mfma_f32_16x16x32_bf16(af, bf[g], acc[m][g], 0, 0, 0);
    }
  }

#pragma unroll
  for (int m = 0; m < 8; ++m) {
    const int ocb = m * 16 + kb * 4;
    float bz0 = bias2[ocb + 0], bz1 = bias2[ocb + 1];
    float bz2 = bias2[ocb + 2], bz3 = bias2[ocb + 3];
#pragma unroll
    for (int g = 0; g < 4; ++g) {
      const int p = p0w + g * 16 + l15;
      bf16x4 hv;
      hv[0] = (__bf16)fmaxf(acc[m][g][0] + bz0, 0.f);
      hv[1] = (__bf16)fmaxf(acc[m][g][1] + bz1, 0.f);
      hv[2] = (__bf16)fmaxf(acc[m][g][2] + bz2, 0.f);
      hv[3] = (__bf16)fmaxf(acc[m][g][3] + bz3, 0.f);
      *(bf16x4*)(h2 + ((size_t)n * 1024 + p) * 128 + ocb) = hv;
    }
  }
}

// ---- kernel 3: 3x3 conv (pad 1) h2 -> out[:, 512:544] ----
// grid: 512 blocks, 4 waves, wave = 32 oc x 64 px. n ASCENDING (h2 recency).
__global__ void __launch_bounds__(256) conv2_kernel(
    const unsigned short* __restrict__ h2, const unsigned short* __restrict__ w2b,
    float* __restrict__ out) {
  const int t = threadIdx.x;
  const int lane = t & 63;
  const int wv = t >> 6;
  const int n = blockIdx.x >> 2;
  const int pbase = (blockIdx.x & 3) * 256 + wv * 64;
  const int l15 = lane & 15;
  const int kb = lane >> 4;

  f32x4 acc[2][4];
#pragma unroll
  for (int m = 0; m < 2; ++m)
#pragma unroll
    for (int g = 0; g < 4; ++g) acc[m][g] = (f32x4){0.f, 0.f, 0.f, 0.f};

  const unsigned short* __restrict__ h2n = h2 + (size_t)n * 1024 * 128;

#pragma unroll
  for (int tap = 0; tap < 9; ++tap) {
    const int dy = tap / 3 - 1;
    const int dx = tap % 3 - 1;
#pragma unroll
    for (int c0 = 0; c0 < 128; c0 += 32) {
      const int cb = c0 + kb * 8;
      bf16x8 af[2];
#pragma unroll
      for (int m = 0; m < 2; ++m)
        af[m] = *(const bf16x8*)(w2b + (size_t)(m * 16 + l15) * 1152 + tap * 128 + cb);
#pragma unroll
      for (int g = 0; g < 4; ++g) {
        const int p = pbase + g * 16 + l15;
        const int y = (p >> 5) & 31;
        const int xx = p & 31;
        const int y2 = y + dy;
        const int x2 = xx + dx;
        bf16x8 bv = __builtin_bit_cast(bf16x8, (ushort8){0, 0, 0, 0, 0, 0, 0, 0});
        if (y2 >= 0 && y2 < 32 && x2 >= 0 && x2 < 32)
          bv = *(const bf16x8*)(h2n + ((size_t)(y2 * 32 + x2)) * 128 + cb);
#pragma unroll
        for (int m = 0; m < 2; ++m)
          acc[m][g] = __builtin_amdgcn_mfma_f32_16x16x32_bf16(af[m], bv, acc[m][g], 0, 0, 0);
      }
    }
  }

#pragma unroll
  for (int m = 0; m < 2; ++m) {
    const int oc = m * 16 + kb * 4;
#pragma unroll
    for (int g = 0; g < 4; ++g) {
      const int p = pbase + g * 16 + l15;
#pragma unroll
      for (int r = 0; r < 4; ++r)
        __builtin_nontemporal_store(
            acc[m][g][r], &out[((size_t)n * 544 + 512 + oc + r) * 1024 + p]);
    }
  }
}

extern "C" void kernel_launch(void* const* d_in, const int* in_sizes, int n_in,
                              void* d_out, int out_size, void* d_ws, size_t ws_size,
                              hipStream_t stream) {
  const float* x = (const float*)d_in[0];
  const float* gamma1 = (const float*)d_in[1];
  const float* beta1 = (const float*)d_in[2];
  const float* w1 = (const float*)d_in[3];
  const float* gamma2 = (const float*)d_in[4];
  const float* beta2 = (const float*)d_in[5];
  const float* mean2 = (const float*)d_in[6];
  const float* var2 = (const float*)d_in[7];
  const float* w2 = (const float*)d_in[8];
  float* out = (float*)d_out;

  char* ws = (char*)d_ws;
  unsigned short* h2 = (unsigned short*)ws;
  unsigned short* xbf = (unsigned short*)(ws + 33554432);
  unsigned short* w1b = (unsigned short*)(ws + 167772160);
  unsigned short* w2b = (unsigned short*)(ws + 167903232);
  float* bias2 = (float*)(ws + 167976960);
  float* s1 = (float*)(ws + 167977472);
  float* b1 = (float*)(ws + 167979520);
  float* psum = (float*)(ws + 167981568);
  float* psq = (float*)(ws + 170078720);

  k1_kernel<<<1425, 256, 0, stream>>>(x, out, xbf, psum, psq,
                                      w1, gamma2, beta2, mean2, var2, w2,
                                      w1b, w2b, bias2);
  reduce_kernel<<<512, 256, 0, stream>>>(psum, psq, gamma1, beta1, s1, b1);
  conv1_kernel<<<512, 256, 0, stream>>>(xbf, w1b, s1, b1, bias2, h2);
  conv2_kernel<<<512, 256, 0, stream>>>(h2, w2b, out);
}

// Round 7
// 199.327 us; speedup vs baseline: 1.5441x; 1.1598x over previous
//
#include <hip/hip_runtime.h>

#define EPS 1e-5f

typedef __bf16 bf16x8 __attribute__((ext_vector_type(8)));
typedef __bf16 bf16x4 __attribute__((ext_vector_type(4)));
typedef unsigned short ushort8 __attribute__((ext_vector_type(8)));
typedef float f32x4 __attribute__((ext_vector_type(4)));

static __device__ __forceinline__ unsigned short f2bf(float f) {
  unsigned int u = __float_as_uint(f);
  u += 0x7fffu + ((u >> 16) & 1u);
  return (unsigned short)(u >> 16);
}

// ---------------- ws layout (bytes) ----------------
// h2   (bf16, NHWC [128][1024][128])             : 0 .. 33554432
// w1b  (bf16, [128 oc][512 c], bn2-scale folded) : 33554432 .. +131072
// w2b  (bf16, [32 oc][9 tap][128 c])             : 33685504 .. +73728
// bias2(f32 [128])                               : 33759232 .. +512
// s1   (f32 [512])                               : 33759744 .. +2048
// b1   (f32 [512])                               : 33761792 .. +2048
// psum (f32 [512][8])                            : 33763840 .. +16384
// psq  (f32 [512][8])                            : 33780224 .. +16384

// ---- kernel 1: bn1 partial stats + concat-copy of x (+ weight prep blocks) ----
// blocks 0..4095: (nq,c), nq-major so n=112..127 x-lines are freshest in L3.
// x loads PLAIN (allocate L3 for conv1 reuse); out stores nontemporal.
__global__ void __launch_bounds__(256) k1_kernel(
    const float* __restrict__ x, float* __restrict__ out,
    float* __restrict__ psum, float* __restrict__ psq,
    const float* __restrict__ w1, const float* __restrict__ gamma2,
    const float* __restrict__ beta2, const float* __restrict__ mean2,
    const float* __restrict__ var2, const float* __restrict__ w2,
    unsigned short* __restrict__ w1b, unsigned short* __restrict__ w2b,
    float* __restrict__ bias2) {
  const int t = threadIdx.x;
  if (blockIdx.x >= 4096) {
    int idx = (blockIdx.x - 4096) * 256 + t;
    if (idx < 128 * 512) {
      int oc = idx >> 9;
      float s2 = gamma2[oc] * rsqrtf(var2[oc] + EPS);
      w1b[idx] = f2bf(w1[idx] * s2);
    } else if (idx < 128 * 512 + 32 * 1152) {
      int i2 = idx - 128 * 512;
      int oc = i2 / 1152;
      int rem = i2 - oc * 1152;
      int tap = rem >> 7;
      int c = rem & 127;
      w2b[i2] = f2bf(w2[(oc * 128 + c) * 9 + tap]);
    } else if (idx < 128 * 512 + 32 * 1152 + 128) {
      int oc = idx - (128 * 512 + 32 * 1152);
      float s2 = gamma2[oc] * rsqrtf(var2[oc] + EPS);
      bias2[oc] = beta2[oc] - mean2[oc] * s2;
    }
    return;
  }
  const int c = blockIdx.x & 511;
  const int nq = blockIdx.x >> 9;
  float sum = 0.f, sq = 0.f;
  const f32x4* __restrict__ x4 = (const f32x4*)x;
  f32x4* out4 = (f32x4*)out;
#pragma unroll 8
  for (int i = 0; i < 16; ++i) {
    const int n = nq * 16 + i;
    f32x4 v = x4[(((size_t)n * 512 + c) << 8) + t];
    __builtin_nontemporal_store(v, &out4[(((size_t)n * 544 + c) << 8) + t]);
    sum += v[0] + v[1] + v[2] + v[3];
    sq += v[0] * v[0] + v[1] * v[1] + v[2] * v[2] + v[3] * v[3];
  }
  __shared__ float ls[2][4];
  for (int off = 32; off > 0; off >>= 1) {
    sum += __shfl_down(sum, off);
    sq += __shfl_down(sq, off);
  }
  const int w = t >> 6;
  if ((t & 63) == 0) { ls[0][w] = sum; ls[1][w] = sq; }
  __syncthreads();
  if (t == 0) {
    psum[c * 8 + nq] = ls[0][0] + ls[0][1] + ls[0][2] + ls[0][3];
    psq[c * 8 + nq] = ls[1][0] + ls[1][1] + ls[1][2] + ls[1][3];
  }
}

// ---- kernel 1b: finalize bn1 scale/shift (deterministic) ----
__global__ void reduce_kernel(const float* __restrict__ psum,
                              const float* __restrict__ psq,
                              const float* __restrict__ g1,
                              const float* __restrict__ be1,
                              float* __restrict__ s1, float* __restrict__ b1) {
  int c = blockIdx.x * 256 + threadIdx.x;
  if (c < 512) {
    float S = 0.f, Q = 0.f;
#pragma unroll
    for (int q = 0; q < 8; ++q) { S += psum[c * 8 + q]; Q += psq[c * 8 + q]; }
    float mean = S * (1.0f / 131072.0f);
    float var = Q * (1.0f / 131072.0f) - mean * mean;
    float s = g1[c] * rsqrtf(var + EPS);
    s1[c] = s;
    b1[c] = be1[c] - mean * s;
  }
}

// ---- kernel 2: bn1+relu -> 1x1 conv -> bn2+relu -> h2 (bf16 NHWC), direct from x ----
// grid: 512 blocks (128 n x 4 quarters), 4 waves. Wave stages 8 channels x 256 px
// coalesced (1KB/instr), LDS tile [32 ch][260 px] bf16, u16 fragment reads.
// n DESCENDING: consume the x lines k1 read last (L3 tail).
__global__ void __launch_bounds__(256, 2) conv1_kernel(
    const float* __restrict__ x, const unsigned short* __restrict__ w1b,
    const float* __restrict__ s1, const float* __restrict__ b1,
    const float* __restrict__ bias2, unsigned short* __restrict__ h2) {
  const int t = threadIdx.x;
  __shared__ float s1s[512], b1s[512];
  __shared__ __align__(16) unsigned short tile[32 * 260];
  for (int cc = t; cc < 512; cc += 256) {
    s1s[cc] = s1[cc];
    b1s[cc] = b1[cc];
  }
  __syncthreads();

  const int lane = t & 63;
  const int wv = t >> 6;
  const int n = 127 - (blockIdx.x >> 2);
  const int q = blockIdx.x & 3;
  const int l15 = lane & 15;
  const int kb = lane >> 4;

  f32x4 acc[8][4];
#pragma unroll
  for (int m = 0; m < 8; ++m)
#pragma unroll
    for (int g = 0; g < 4; ++g) acc[m][g] = (f32x4){0.f, 0.f, 0.f, 0.f};

  // quarter base: x[n][.][q*256 ..]; f32x4 index = ch*256 + lane
  const f32x4* __restrict__ xq = (const f32x4*)(x + (size_t)n * 524288 + q * 256);

  f32x4 v[8];
#pragma unroll
  for (int i = 0; i < 8; ++i)
    v[i] = xq[(size_t)(wv * 8 + i) * 256 + lane];

  for (int k = 0; k < 16; ++k) {
    const int c0 = k * 32;
    // stage current K-slice (bn1+relu+cvt), prefetch next
#pragma unroll
    for (int i = 0; i < 8; ++i) {
      const int c = c0 + wv * 8 + i;
      const float s = s1s[c], b = b1s[c];
      bf16x4 bv;
      bv[0] = (__bf16)fmaxf(fmaf(v[i][0], s, b), 0.f);
      bv[1] = (__bf16)fmaxf(fmaf(v[i][1], s, b), 0.f);
      bv[2] = (__bf16)fmaxf(fmaf(v[i][2], s, b), 0.f);
      bv[3] = (__bf16)fmaxf(fmaf(v[i][3], s, b), 0.f);
      *(bf16x4*)&tile[(size_t)(wv * 8 + i) * 260 + 4 * lane] = bv;
    }
    if (k < 15) {
#pragma unroll
      for (int i = 0; i < 8; ++i)
        v[i] = xq[(size_t)(c0 + 32 + wv * 8 + i) * 256 + lane];
    }
    __syncthreads();
    // fragments (u16 reads, ~4-way) + MFMA
    bf16x8 bf[4];
#pragma unroll
    for (int g = 0; g < 4; ++g) {
      const int pl = wv * 64 + g * 16 + l15;
      bf16x8 tmp;
#pragma unroll
      for (int j = 0; j < 8; ++j)
        tmp[j] = __builtin_bit_cast(__bf16, tile[(kb * 8 + j) * 260 + pl]);
      bf[g] = tmp;
    }
#pragma unroll
    for (int m = 0; m < 8; ++m) {
      bf16x8 af = *(const bf16x8*)(w1b + (size_t)(m * 16 + l15) * 512 + c0 + kb * 8);
#pragma unroll
      for (int g = 0; g < 4; ++g)
        acc[m][g] = __builtin_amdgcn_mfma_f32_16x16x32_bf16(af, bf[g], acc[m][g], 0, 0, 0);
    }
    __syncthreads();
  }

  // epilogue: h2[n][p][oc] = relu(acc + bias2)  (plain stores -> L3 for conv2)
#pragma unroll
  for (int m = 0; m < 8; ++m) {
    const int ocb = m * 16 + kb * 4;
    float bz0 = bias2[ocb + 0], bz1 = bias2[ocb + 1];
    float bz2 = bias2[ocb + 2], bz3 = bias2[ocb + 3];
#pragma unroll
    for (int g = 0; g < 4; ++g) {
      const int p = q * 256 + wv * 64 + g * 16 + l15;
      bf16x4 hv;
      hv[0] = (__bf16)fmaxf(acc[m][g][0] + bz0, 0.f);
      hv[1] = (__bf16)fmaxf(acc[m][g][1] + bz1, 0.f);
      hv[2] = (__bf16)fmaxf(acc[m][g][2] + bz2, 0.f);
      hv[3] = (__bf16)fmaxf(acc[m][g][3] + bz3, 0.f);
      *(bf16x4*)(h2 + ((size_t)n * 1024 + p) * 128 + ocb) = hv;
    }
  }
}

// ---- kernel 3: 3x3 conv (pad 1) h2 -> out[:, 512:544] ----
// grid: 512 blocks, 4 waves, wave = 32 oc x 64 px. n ASCENDING (h2 recency vs conv1).
__global__ void __launch_bounds__(256) conv2_kernel(
    const unsigned short* __restrict__ h2, const unsigned short* __restrict__ w2b,
    float* __restrict__ out) {
  const int t = threadIdx.x;
  const int lane = t & 63;
  const int wv = t >> 6;
  const int n = blockIdx.x >> 2;
  const int pbase = (blockIdx.x & 3) * 256 + wv * 64;
  const int l15 = lane & 15;
  const int kb = lane >> 4;

  f32x4 acc[2][4];
#pragma unroll
  for (int m = 0; m < 2; ++m)
#pragma unroll
    for (int g = 0; g < 4; ++g) acc[m][g] = (f32x4){0.f, 0.f, 0.f, 0.f};

  const unsigned short* __restrict__ h2n = h2 + (size_t)n * 1024 * 128;

#pragma unroll
  for (int tap = 0; tap < 9; ++tap) {
    const int dy = tap / 3 - 1;
    const int dx = tap % 3 - 1;
#pragma unroll
    for (int c0 = 0; c0 < 128; c0 += 32) {
      const int cb = c0 + kb * 8;
      bf16x8 af[2];
#pragma unroll
      for (int m = 0; m < 2; ++m)
        af[m] = *(const bf16x8*)(w2b + (size_t)(m * 16 + l15) * 1152 + tap * 128 + cb);
#pragma unroll
      for (int g = 0; g < 4; ++g) {
        const int p = pbase + g * 16 + l15;
        const int y = (p >> 5) & 31;
        const int xx = p & 31;
        const int y2 = y + dy;
        const int x2 = xx + dx;
        bf16x8 bv = __builtin_bit_cast(bf16x8, (ushort8){0, 0, 0, 0, 0, 0, 0, 0});
        if (y2 >= 0 && y2 < 32 && x2 >= 0 && x2 < 32)
          bv = *(const bf16x8*)(h2n + ((size_t)(y2 * 32 + x2)) * 128 + cb);
#pragma unroll
        for (int m = 0; m < 2; ++m)
          acc[m][g] = __builtin_amdgcn_mfma_f32_16x16x32_bf16(af[m], bv, acc[m][g], 0, 0, 0);
      }
    }
  }

#pragma unroll
  for (int m = 0; m < 2; ++m) {
    const int oc = m * 16 + kb * 4;
#pragma unroll
    for (int g = 0; g < 4; ++g) {
      const int p = pbase + g * 16 + l15;
#pragma unroll
      for (int r = 0; r < 4; ++r)
        __builtin_nontemporal_store(
            acc[m][g][r], &out[((size_t)n * 544 + 512 + oc + r) * 1024 + p]);
    }
  }
}

extern "C" void kernel_launch(void* const* d_in, const int* in_sizes, int n_in,
                              void* d_out, int out_size, void* d_ws, size_t ws_size,
                              hipStream_t stream) {
  const float* x = (const float*)d_in[0];
  const float* gamma1 = (const float*)d_in[1];
  const float* beta1 = (const float*)d_in[2];
  const float* w1 = (const float*)d_in[3];
  const float* gamma2 = (const float*)d_in[4];
  const float* beta2 = (const float*)d_in[5];
  const float* mean2 = (const float*)d_in[6];
  const float* var2 = (const float*)d_in[7];
  const float* w2 = (const float*)d_in[8];
  float* out = (float*)d_out;

  char* ws = (char*)d_ws;
  unsigned short* h2 = (unsigned short*)ws;
  unsigned short* w1b = (unsigned short*)(ws + 33554432);
  unsigned short* w2b = (unsigned short*)(ws + 33685504);
  float* bias2 = (float*)(ws + 33759232);
  float* s1 = (float*)(ws + 33759744);
  float* b1 = (float*)(ws + 33761792);
  float* psum = (float*)(ws + 33763840);
  float* psq = (float*)(ws + 33780224);

  k1_kernel<<<4497, 256, 0, stream>>>(x, out, psum, psq,
                                      w1, gamma2, beta2, mean2, var2, w2,
                                      w1b, w2b, bias2);
  reduce_kernel<<<2, 256, 0, stream>>>(psum, psq, gamma1, beta1, s1, b1);
  conv1_kernel<<<512, 256, 0, stream>>>(x, w1b, s1, b1, bias2, h2);
  conv2_kernel<<<512, 256, 0, stream>>>(h2, w2b, out);
}